// Round 7
// baseline (127.892 us; speedup 1.0000x reference)
//
#include <hip/hip_runtime.h>

// 4-level db4 wavedec (symmetric mode) + 6 stats per band.
// One block of 512 threads per signal. Levels: 16384 -> 8195 -> 4101 -> 2054 -> 1030.
//
// V8 = V3's proven skeleton (ping-pong LDS A/B, 1 barrier/level, strided
// quad-per-thread, scalar-FMA dots @90us) + three local trims:
//  1. zc-extra d-dot (8 FMA/quad) replaced by __shfl_down(d0,1): quad k+1's
//     d0 is computed simultaneously by lane+1 (same chunk => same iteration).
//     Exactly the lanes whose neighbor is NOT co-executing self-compute:
//     lane63 (cross-wave/chunk) and k==NQ-1 (neighbor idle or tail thread).
//     Values bitwise-identical to V3 (same inputs, same FMA order).
//  2. zero-crossings via sign-bit mask + popc((m ^ m>>1) & 15).
//  3. in-loop reduce shortened to 4 butterfly steps (xor 32,16,8,4); lanes
//     0-3/wave write 32 partials/band; finalize = 5 waves (one per band),
//     each doing 5 LDS reads + 5-step shuffle. red 0.8KB -> 3.2KB; LDS total
//     52.4KB, still 3 blocks/CU.
//  4. L1 trip count compile-time (4) + #pragma unroll 2 for load/compute overlap.
// History: V4 in-place per-chunk barriers 103us; V5 packed v2f 131us (scratch);
// V6 hold-in-regs @(512,8) 131us (spill); V7 contiguous spans+swizzle 91.8us
// (neutral: swizzle/addressing overhead ate the arithmetic savings).
// Band order: [cA4, cD4, cD3, cD2, cD1] x [mean_abs, std, rms, max, energy, zc].

#define T0 16384
#define BLK 512
#define NW (BLK / 64)

// Reversed db4 decomposition filters (lax correlation == pywt convolution).
constexpr float FLO[8] = {
     0.23037781330885523f,  0.7148465705525415f,   0.6308807679295904f,
    -0.02798376941698385f, -0.18703481171888114f,  0.030841381835986965f,
     0.032883011666982945f, -0.010597401784997278f };
constexpr float FHI[8] = {
    -0.010597401784997278f, -0.032883011666982945f, 0.030841381835986965f,
     0.18703481171888114f,  -0.02798376941698385f,  -0.6308807679295904f,
     0.7148465705525415f,   -0.23037781330885523f };

// symmetric extension fold: ext index t -> valid index (single fold suffices;
// our windows stay within [-6, L+10]).
__device__ __forceinline__ float getsym(const float* __restrict__ s, int t, int L) {
    if (t < 0) t = -1 - t;
    else if (t >= L) t = 2 * L - 1 - t;
    return s[t];
}

// 1 if sign bits differ (zero-crossing). Matches sign()-diff for nonzero data.
__device__ __forceinline__ float zcstep(float p, float q) {
    return ((__float_as_int(p) ^ __float_as_int(q)) < 0) ? 1.f : 0.f;
}

// 4-step butterfly (xor 32,16,8,4): every lane holds the sum over its
// lane%4 class; lanes 0-3 of each wave write partial (wave*4+lane) of 32.
// NO barrier here (deferred to finalize).
__device__ __forceinline__ void band_reduce(float sabs, float ssum, float ssq,
                                            float smax, float zc,
                                            int band, float* __restrict__ red) {
    #pragma unroll
    for (int off = 32; off >= 4; off >>= 1) {
        sabs += __shfl_xor(sabs, off, 64);
        ssum += __shfl_xor(ssum, off, 64);
        ssq  += __shfl_xor(ssq,  off, 64);
        smax  = fmaxf(smax, __shfl_xor(smax, off, 64));
        zc   += __shfl_xor(zc,   off, 64);
    }
    const int lane = (int)threadIdx.x & 63;
    if (lane < 4) {
        const int wave = (int)threadIdx.x >> 6;
        float* r = red + ((band * NW + wave) * 4 + lane) * 5;
        r[0] = sabs; r[1] = ssum; r[2] = ssq; r[3] = smax; r[4] = zc;
    }
}

// Load the 20-float window for quad k: v[j] = src_ext[8k-8+j]. Fast path is
// 5x float4 (16B aligned, 32B lane stride -> conflict-free b128 in LDS);
// boundary threads take the folded scalar path (only v[2..17] are consumed).
__device__ __forceinline__ void load_win(const float* __restrict__ src, int L, int k,
                                         float* __restrict__ v) {
    const int w = 8 * k - 8;
    if (w >= 0 && w + 20 <= L) {
        #pragma unroll
        for (int q = 0; q < 5; ++q) {
            const float4 t = *reinterpret_cast<const float4*>(src + w + 4 * q);
            v[4*q+0] = t.x; v[4*q+1] = t.y; v[4*q+2] = t.z; v[4*q+3] = t.w;
        }
    } else {
        #pragma unroll
        for (int j = 2; j < 18; ++j) v[j] = getsym(src, w + j, L);
    }
}

// One DWT level, quad-per-thread (strided k = c*BLK + tid).
// LAST: also accumulate cA stats into band 0 and skip the dst write.
template<bool LAST, int L, int o, int DBAND>
__device__ __forceinline__ void dwt_level(const float* __restrict__ src,
                                          float* __restrict__ dst,
                                          float* __restrict__ red) {
    constexpr int NQ = (o - 1) >> 2;     // quads with 4 valid outputs + valid extra
    const int tid = (int)threadIdx.x;
    const bool l63 = (tid & 63) == 63;
    float sabs = 0.f, ssum = 0.f, ssq = 0.f, smax = 0.f, zc = 0.f;       // cD
    float sabsA = 0.f, ssumA = 0.f, ssqA = 0.f, smaxA = 0.f, zcA = 0.f;  // cA (LAST)

    auto body = [&](int k) {
        float v[20];
        load_win(src, L, k, v);
        float a0=0.f,a1=0.f,a2=0.f,a3=0.f,d0=0.f,d1=0.f,d2=0.f,d3=0.f;
        #pragma unroll
        for (int m = 0; m < 8; ++m) {
            const float lo = FLO[m], hi = FHI[m];
            a0 = fmaf(v[2+m], lo, a0);  d0 = fmaf(v[2+m], hi, d0);
            a1 = fmaf(v[4+m], lo, a1);  d1 = fmaf(v[4+m], hi, d1);
            a2 = fmaf(v[6+m], lo, a2);  d2 = fmaf(v[6+m], hi, d2);
            a3 = fmaf(v[8+m], lo, a3);  d3 = fmaf(v[8+m], hi, d3);
        }
        // next quad's d0 (= our d at 4k+4) from the co-executing neighbor lane.
        float dn = __shfl_down(d0, 1, 64);
        float an = 0.f;
        if constexpr (LAST) an = __shfl_down(a0, 1, 64);
        if (l63 || k + 1 >= NQ) {        // neighbor not co-executing: self-compute
            float t = 0.f;
            #pragma unroll
            for (int m = 0; m < 8; ++m) t = fmaf(v[10+m], FHI[m], t);
            dn = t;
            if constexpr (LAST) {
                float u = 0.f;
                #pragma unroll
                for (int m = 0; m < 8; ++m) u = fmaf(v[10+m], FLO[m], u);
                an = u;
            }
        }
        if constexpr (!LAST)
            *reinterpret_cast<float4*>(dst + 4 * k) = make_float4(a0, a1, a2, a3);
        sabs += fabsf(d0) + fabsf(d1) + fabsf(d2) + fabsf(d3);
        ssum += d0 + d1 + d2 + d3;
        ssq = fmaf(d0, d0, ssq); ssq = fmaf(d1, d1, ssq);
        ssq = fmaf(d2, d2, ssq); ssq = fmaf(d3, d3, ssq);
        smax = fmaxf(smax, fmaxf(fmaxf(fabsf(d0), fabsf(d1)),
                                 fmaxf(fabsf(d2), fabsf(d3))));
        unsigned mk = (__float_as_uint(d0) >> 31)
                    | ((__float_as_uint(d1) >> 31) << 1)
                    | ((__float_as_uint(d2) >> 31) << 2)
                    | ((__float_as_uint(d3) >> 31) << 3)
                    | ((__float_as_uint(dn) >> 31) << 4);
        zc += (float)__popc((mk ^ (mk >> 1)) & 15u);
        if constexpr (LAST) {
            sabsA += fabsf(a0) + fabsf(a1) + fabsf(a2) + fabsf(a3);
            ssumA += a0 + a1 + a2 + a3;
            ssqA = fmaf(a0, a0, ssqA); ssqA = fmaf(a1, a1, ssqA);
            ssqA = fmaf(a2, a2, ssqA); ssqA = fmaf(a3, a3, ssqA);
            smaxA = fmaxf(smaxA, fmaxf(fmaxf(fabsf(a0), fabsf(a1)),
                                       fmaxf(fabsf(a2), fabsf(a3))));
            unsigned ma = (__float_as_uint(a0) >> 31)
                        | ((__float_as_uint(a1) >> 31) << 1)
                        | ((__float_as_uint(a2) >> 31) << 2)
                        | ((__float_as_uint(a3) >> 31) << 3)
                        | ((__float_as_uint(an) >> 31) << 4);
            zcA += (float)__popc((ma ^ (ma >> 1)) & 15u);
        }
    };

    if constexpr ((NQ % BLK) == 0) {     // L1: uniform trip (4) -> pipelined
        #pragma unroll 2
        for (int c = 0; c < NQ / BLK; ++c) body(c * BLK + tid);
    } else {
        for (int k = tid; k < NQ; k += BLK) body(k);
    }

    // Exactly one leftover quad (k=NQ) per level; thread BLK-1 runs it guarded.
    if (tid == BLK - 1) {
        constexpr int k = NQ;
        float v[20], a[5], d[5];
        #pragma unroll
        for (int j = 2; j < 18; ++j) v[j] = getsym(src, 8 * k - 8 + j, L);
        #pragma unroll
        for (int i = 0; i < 5; ++i) { a[i] = 0.f; d[i] = 0.f; }
        #pragma unroll
        for (int i = 0; i < 5; ++i) {
            #pragma unroll
            for (int m = 0; m < 8; ++m) {
                a[i] = fmaf(v[2*i+2+m], FLO[m], a[i]);
                d[i] = fmaf(v[2*i+2+m], FHI[m], d[i]);
            }
        }
        #pragma unroll
        for (int i = 0; i < 4; ++i) {
            const int p = 4 * k + i;
            if (p < o) {
                sabs += fabsf(d[i]); ssum += d[i]; ssq = fmaf(d[i], d[i], ssq);
                smax = fmaxf(smax, fabsf(d[i]));
                if (p + 1 < o) zc += zcstep(d[i], d[i+1]);
                if constexpr (LAST) {
                    sabsA += fabsf(a[i]); ssumA += a[i]; ssqA = fmaf(a[i], a[i], ssqA);
                    smaxA = fmaxf(smaxA, fabsf(a[i]));
                    if (p + 1 < o) zcA += zcstep(a[i], a[i+1]);
                } else {
                    dst[p] = a[i];
                }
            }
        }
    }

    band_reduce(sabs, ssum, ssq, smax, zc, DBAND, red);
    if constexpr (LAST) band_reduce(sabsA, ssumA, ssqA, smaxA, zcA, 0, red);
}

__global__ void __launch_bounds__(BLK, 6)
wavelet_feat_kernel(const float* __restrict__ x, float* __restrict__ out) {
    __shared__ __align__(16) float A[8196];     // cA1, later cA3
    __shared__ __align__(16) float B[4104];     // cA2
    __shared__ float red[5 * 32 * 5];           // [band][partial 0..31][stat]

    const float* src0 = x + (size_t)blockIdx.x * T0;
    float* outp = out + (size_t)blockIdx.x * 30;

    // band index: 0=cA4 1=cD4 2=cD3 3=cD2 4=cD1
    dwt_level<false, 16384, 8195, 4>(src0, A, red);     // L1: x -> A,  cD1
    __syncthreads();
    dwt_level<false,  8195, 4101, 3>(A,    B, red);     // L2: A -> B,  cD2
    __syncthreads();
    dwt_level<false,  4101, 2054, 2>(B,    A, red);     // L3: B -> A,  cD3
    __syncthreads();
    dwt_level<true,   2054, 1030, 1>(A, nullptr, red);  // L4: cD4 + cA4 stats
    __syncthreads();                                    // red[] complete

    // Finalize: wave w handles band w (parallel, replaces thread-0-serial).
    const int wave = (int)threadIdx.x >> 6, lane = (int)threadIdx.x & 63;
    if (wave < 5) {
        float a = 0.f, s = 0.f, q = 0.f, m = 0.f, z = 0.f;
        if (lane < 32) {
            const float* r = red + (wave * 32 + lane) * 5;
            a = r[0]; s = r[1]; q = r[2]; m = r[3]; z = r[4];
        }
        #pragma unroll
        for (int off = 16; off > 0; off >>= 1) {   // lanes 32-63 hold zeros
            a += __shfl_xor(a, off, 64);
            s += __shfl_xor(s, off, 64);
            q += __shfl_xor(q, off, 64);
            m  = fmaxf(m, __shfl_xor(m, off, 64));
            z += __shfl_xor(z, off, 64);
        }
        if (lane == 0) {
            const int band = wave;
            const int o = (band <= 1) ? 1030 : (band == 2 ? 2054 : (band == 3 ? 4101 : 8195));
            const float inv  = 1.0f / (float)o;
            const float mean = s * inv;
            const float var  = q * inv - mean * mean;
            float* op = outp + band * 6;
            op[0] = a * inv;                  // mean_abs
            op[1] = sqrtf(fmaxf(var, 0.f));   // std (population)
            op[2] = sqrtf(q * inv);           // rms
            op[3] = m;                        // max_abs
            op[4] = q;                        // energy
            op[5] = z * inv;                  // zero-crossing rate
        }
    }
}

extern "C" void kernel_launch(void* const* d_in, const int* in_sizes, int n_in,
                              void* d_out, int out_size, void* d_ws, size_t ws_size,
                              hipStream_t stream) {
    const float* x = (const float*)d_in[0];
    float* out = (float*)d_out;
    const int nsig = in_sizes[0] / T0;   // 64*64 = 4096
    hipLaunchKernelGGL(wavelet_feat_kernel, dim3(nsig), dim3(BLK), 0, stream, x, out);
}

// Round 8
// 106.859 us; speedup vs baseline: 1.1968x; 1.1968x over previous
//
#include <hip/hip_runtime.h>

// 4-level db4 wavedec (symmetric mode) + 6 stats per band.
// One block of 512 threads per signal. Levels: 16384 -> 8195 -> 4101 -> 2054 -> 1030.
//
// V9 = V3's proven skeleton with V8's three trims re-expressed in V3's exact
// syntactic shape (V8's lambda + unroll-2 caused scratch spill: WRITE 91MB).
// HARD RULES (3 codegen regressions: V5 packed v2f, V6 hold-in-regs, V8 lambda):
//   no lambdas, no outer unroll pragmas, scalar accumulators in the hot path,
//   keep the strided quad loop + 5x float4 load_win byte-identical to V3.
// Trims vs V3:
//  1. zc-extra d-dot (8 FMA/quad) -> __shfl_down(d0,1): quad k+1's d0 is
//     computed by lane+1 in the same strided iteration. Lanes whose neighbor
//     is not co-executing (lane63, or k+1>=NQ incl. lone-thread iterations
//     and L4's thread 256) self-compute the extra dot.
//  2. zero-crossings via 5-bit sign mask + popc((m ^ m>>1) & 15).
//  3. reduce shortened to 4 butterfly steps (xor 32,16,8,4); lanes 0-3/wave
//     write 32 partials/band; finalize is wave-parallel (wave w = band w).
//     red 3.2KB; LDS total 52.7KB -> still 3 blocks/CU.
// Band order: [cA4, cD4, cD3, cD2, cD1] x [mean_abs, std, rms, max, energy, zc].

#define T0 16384
#define BLK 512
#define NW (BLK / 64)

// Reversed db4 decomposition filters (lax correlation == pywt convolution).
constexpr float FLO[8] = {
     0.23037781330885523f,  0.7148465705525415f,   0.6308807679295904f,
    -0.02798376941698385f, -0.18703481171888114f,  0.030841381835986965f,
     0.032883011666982945f, -0.010597401784997278f };
constexpr float FHI[8] = {
    -0.010597401784997278f, -0.032883011666982945f, 0.030841381835986965f,
     0.18703481171888114f,  -0.02798376941698385f,  -0.6308807679295904f,
     0.7148465705525415f,   -0.23037781330885523f };

// symmetric extension fold: ext index t -> valid index (single fold suffices;
// our windows stay within [-6, L+10]).
__device__ __forceinline__ float getsym(const float* __restrict__ s, int t, int L) {
    if (t < 0) t = -1 - t;
    else if (t >= L) t = 2 * L - 1 - t;
    return s[t];
}

// 1 if sign bits differ (zero-crossing). Matches sign()-diff for nonzero data.
__device__ __forceinline__ float zcstep(float p, float q) {
    return ((__float_as_int(p) ^ __float_as_int(q)) < 0) ? 1.f : 0.f;
}

// 4-step butterfly (xor 32,16,8,4): each lane ends with the sum over its
// lane%4 class (16 lanes); lanes 0-3 of each wave write 4 partials -> 32/band.
// NO barrier here (deferred to finalize).
__device__ __forceinline__ void band_reduce(float sabs, float ssum, float ssq,
                                            float smax, float zc,
                                            int band, float* __restrict__ red) {
    #pragma unroll
    for (int off = 32; off >= 4; off >>= 1) {
        sabs += __shfl_xor(sabs, off, 64);
        ssum += __shfl_xor(ssum, off, 64);
        ssq  += __shfl_xor(ssq,  off, 64);
        smax  = fmaxf(smax, __shfl_xor(smax, off, 64));
        zc   += __shfl_xor(zc,   off, 64);
    }
    const int lane = (int)threadIdx.x & 63;
    if (lane < 4) {
        const int wave = (int)threadIdx.x >> 6;
        float* r = red + ((band * NW + wave) * 4 + lane) * 5;
        r[0] = sabs; r[1] = ssum; r[2] = ssq; r[3] = smax; r[4] = zc;
    }
}

// Load the 20-float window for quad k: v[j] = src_ext[8k-8+j]. Fast path is
// 5x float4 (16B aligned, 32B lane stride -> conflict-free b128 in LDS);
// boundary threads take the folded scalar path (only v[2..17] are consumed).
__device__ __forceinline__ void load_win(const float* __restrict__ src, int L, int k,
                                         float* __restrict__ v) {
    const int w = 8 * k - 8;
    if (w >= 0 && w + 20 <= L) {
        #pragma unroll
        for (int q = 0; q < 5; ++q) {
            const float4 t = *reinterpret_cast<const float4*>(src + w + 4 * q);
            v[4*q+0] = t.x; v[4*q+1] = t.y; v[4*q+2] = t.z; v[4*q+3] = t.w;
        }
    } else {
        #pragma unroll
        for (int j = 2; j < 18; ++j) v[j] = getsym(src, w + j, L);
    }
}

// One DWT level, quad-per-thread (strided k = tid, tid+BLK, ...), V3 shape.
// LAST: also accumulate cA stats into band 0 and skip the dst write.
template<bool LAST, int L, int o, int DBAND>
__device__ __forceinline__ void dwt_quad_level(const float* __restrict__ src,
                                               float* __restrict__ dst,
                                               float* __restrict__ red) {
    constexpr int NQ = (o - 1) >> 2;
    const int tid = (int)threadIdx.x;
    const bool l63 = (tid & 63) == 63;
    float sabs = 0.f, ssum = 0.f, ssq = 0.f, smax = 0.f, zc = 0.f;       // cD
    float sabsA = 0.f, ssumA = 0.f, ssqA = 0.f, smaxA = 0.f, zcA = 0.f;  // cA (LAST)

    for (int k = tid; k < NQ; k += BLK) {
        float v[20];
        load_win(src, L, k, v);
        float a0=0.f,a1=0.f,a2=0.f,a3=0.f,d0=0.f,d1=0.f,d2=0.f,d3=0.f;
        #pragma unroll
        for (int m = 0; m < 8; ++m) {
            const float lo = FLO[m], hi = FHI[m];
            a0 = fmaf(v[2+m], lo, a0);  d0 = fmaf(v[2+m], hi, d0);
            a1 = fmaf(v[4+m], lo, a1);  d1 = fmaf(v[4+m], hi, d1);
            a2 = fmaf(v[6+m], lo, a2);  d2 = fmaf(v[6+m], hi, d2);
            a3 = fmaf(v[8+m], lo, a3);  d3 = fmaf(v[8+m], hi, d3);
        }
        // Next quad's d0 (= d at position 4k+4) from the co-executing
        // neighbor lane; self-compute where the neighbor isn't co-executing.
        float dn = __shfl_down(d0, 1, 64);
        float an;
        if constexpr (LAST) an = __shfl_down(a0, 1, 64);
        if (l63 || k + 1 >= NQ) {
            float t = 0.f;
            #pragma unroll
            for (int m = 0; m < 8; ++m) t = fmaf(v[10+m], FHI[m], t);
            dn = t;
            if constexpr (LAST) {
                float u = 0.f;
                #pragma unroll
                for (int m = 0; m < 8; ++m) u = fmaf(v[10+m], FLO[m], u);
                an = u;
            }
        }
        if constexpr (!LAST)
            *reinterpret_cast<float4*>(dst + 4 * k) = make_float4(a0, a1, a2, a3);
        sabs += fabsf(d0) + fabsf(d1) + fabsf(d2) + fabsf(d3);
        ssum += d0 + d1 + d2 + d3;
        ssq = fmaf(d0, d0, ssq); ssq = fmaf(d1, d1, ssq);
        ssq = fmaf(d2, d2, ssq); ssq = fmaf(d3, d3, ssq);
        smax = fmaxf(smax, fmaxf(fmaxf(fabsf(d0), fabsf(d1)),
                                 fmaxf(fabsf(d2), fabsf(d3))));
        const unsigned mk = (__float_as_uint(d0) >> 31)
                          | ((__float_as_uint(d1) >> 31) << 1)
                          | ((__float_as_uint(d2) >> 31) << 2)
                          | ((__float_as_uint(d3) >> 31) << 3)
                          | ((__float_as_uint(dn) >> 31) << 4);
        zc += (float)__popc((mk ^ (mk >> 1)) & 15u);
        if constexpr (LAST) {
            sabsA += fabsf(a0) + fabsf(a1) + fabsf(a2) + fabsf(a3);
            ssumA += a0 + a1 + a2 + a3;
            ssqA = fmaf(a0, a0, ssqA); ssqA = fmaf(a1, a1, ssqA);
            ssqA = fmaf(a2, a2, ssqA); ssqA = fmaf(a3, a3, ssqA);
            smaxA = fmaxf(smaxA, fmaxf(fmaxf(fabsf(a0), fabsf(a1)),
                                       fmaxf(fabsf(a2), fabsf(a3))));
            const unsigned ma = (__float_as_uint(a0) >> 31)
                              | ((__float_as_uint(a1) >> 31) << 1)
                              | ((__float_as_uint(a2) >> 31) << 2)
                              | ((__float_as_uint(a3) >> 31) << 3)
                              | ((__float_as_uint(an) >> 31) << 4);
            zcA += (float)__popc((ma ^ (ma >> 1)) & 15u);
        }
    }

    // Exactly one leftover quad (k=NQ) per level; thread BLK-1 runs it guarded.
    if (tid == BLK - 1) {
        constexpr int k = NQ;
        float v[20], a[5], d[5];
        #pragma unroll
        for (int j = 2; j < 18; ++j) v[j] = getsym(src, 8 * k - 8 + j, L);
        #pragma unroll
        for (int i = 0; i < 5; ++i) { a[i] = 0.f; d[i] = 0.f; }
        #pragma unroll
        for (int i = 0; i < 5; ++i) {
            #pragma unroll
            for (int m = 0; m < 8; ++m) {
                a[i] = fmaf(v[2*i+2+m], FLO[m], a[i]);
                d[i] = fmaf(v[2*i+2+m], FHI[m], d[i]);
            }
        }
        #pragma unroll
        for (int i = 0; i < 4; ++i) {
            const int p = 4 * k + i;
            if (p < o) {
                sabs += fabsf(d[i]); ssum += d[i]; ssq = fmaf(d[i], d[i], ssq);
                smax = fmaxf(smax, fabsf(d[i]));
                if (p + 1 < o) zc += zcstep(d[i], d[i+1]);
                if constexpr (LAST) {
                    sabsA += fabsf(a[i]); ssumA += a[i]; ssqA = fmaf(a[i], a[i], ssqA);
                    smaxA = fmaxf(smaxA, fabsf(a[i]));
                    if (p + 1 < o) zcA += zcstep(a[i], a[i+1]);
                } else {
                    dst[p] = a[i];
                }
            }
        }
    }

    band_reduce(sabs, ssum, ssq, smax, zc, DBAND, red);
    if constexpr (LAST) band_reduce(sabsA, ssumA, ssqA, smaxA, zcA, 0, red);
}

__global__ void __launch_bounds__(BLK, 6)
wavelet_feat_kernel(const float* __restrict__ x, float* __restrict__ out) {
    __shared__ __align__(16) float A[8196];     // cA1, later cA3
    __shared__ __align__(16) float B[4104];     // cA2
    __shared__ float red[5 * 32 * 5];           // [band][partial 0..31][stat]

    const float* src0 = x + (size_t)blockIdx.x * T0;
    float* outp = out + (size_t)blockIdx.x * 30;

    // band index: 0=cA4 1=cD4 2=cD3 3=cD2 4=cD1
    dwt_quad_level<false, 16384, 8195, 4>(src0, A, red);     // L1: x -> A,  cD1
    __syncthreads();
    dwt_quad_level<false,  8195, 4101, 3>(A,    B, red);     // L2: A -> B,  cD2
    __syncthreads();
    dwt_quad_level<false,  4101, 2054, 2>(B,    A, red);     // L3: B -> A,  cD3
    __syncthreads();
    dwt_quad_level<true,   2054, 1030, 1>(A, nullptr, red);  // L4: cD4 + cA4
    __syncthreads();                                         // red[] complete

    // Finalize: wave w handles band w (parallel, replaces thread-0-serial).
    const int wave = (int)threadIdx.x >> 6, lane = (int)threadIdx.x & 63;
    if (wave < 5) {
        float a = 0.f, s = 0.f, q = 0.f, m = 0.f, z = 0.f;
        if (lane < 32) {
            const float* r = red + (wave * 32 + lane) * 5;
            a = r[0]; s = r[1]; q = r[2]; m = r[3]; z = r[4];
        }
        #pragma unroll
        for (int off = 16; off > 0; off >>= 1) {   // lanes 32-63 hold zeros
            a += __shfl_xor(a, off, 64);
            s += __shfl_xor(s, off, 64);
            q += __shfl_xor(q, off, 64);
            m  = fmaxf(m, __shfl_xor(m, off, 64));
            z += __shfl_xor(z, off, 64);
        }
        if (lane == 0) {
            const int band = wave;
            const int o = (band <= 1) ? 1030 : (band == 2 ? 2054 : (band == 3 ? 4101 : 8195));
            const float inv  = 1.0f / (float)o;
            const float mean = s * inv;
            const float var  = q * inv - mean * mean;
            float* op = outp + band * 6;
            op[0] = a * inv;                  // mean_abs
            op[1] = sqrtf(fmaxf(var, 0.f));   // std (population)
            op[2] = sqrtf(q * inv);           // rms
            op[3] = m;                        // max_abs
            op[4] = q;                        // energy
            op[5] = z * inv;                  // zero-crossing rate
        }
    }
}

extern "C" void kernel_launch(void* const* d_in, const int* in_sizes, int n_in,
                              void* d_out, int out_size, void* d_ws, size_t ws_size,
                              hipStream_t stream) {
    const float* x = (const float*)d_in[0];
    float* out = (float*)d_out;
    const int nsig = in_sizes[0] / T0;   // 64*64 = 4096
    hipLaunchKernelGGL(wavelet_feat_kernel, dim3(nsig), dim3(BLK), 0, stream, x, out);
}